// Round 1
// baseline (1070.831 us; speedup 1.0000x reference)
//
#include <hip/hip_runtime.h>

#define NN 50000
#define FF 256
#define DD 64
#define HH 4
#define EE 1000000
#define MM 2

// ---------------- GEMM: h = x @ W + b   [N,256] = [N,256]@[256,256] ----------------
__global__ __launch_bounds__(256) void k_gemm(const float* __restrict__ x,
                                              const float* __restrict__ W,
                                              const float* __restrict__ bias,
                                              float* __restrict__ h) {
  __shared__ float Ast[16][68];  // [BK][BM+pad], transposed A tile, 16B-aligned rows
  __shared__ float Bs[16][68];   // [BK][BN+pad]
  const int t  = threadIdx.x;
  const int tx = t & 15, ty = t >> 4;
  const int r0 = blockIdx.x * 64, c0 = blockIdx.y * 64;
  float acc[4][4] = {};

  for (int k0 = 0; k0 < FF; k0 += 16) {
    // stage A: thread t loads float4 of x[row][k0 + 4*(t&3) ..], scatters transposed
    {
      int arow = t >> 2, akq = (t & 3) * 4;
      int gr = r0 + arow; if (gr >= NN) gr = NN - 1;
      float4 av = *reinterpret_cast<const float4*>(x + (size_t)gr * FF + k0 + akq);
      Ast[akq + 0][arow] = av.x;
      Ast[akq + 1][arow] = av.y;
      Ast[akq + 2][arow] = av.z;
      Ast[akq + 3][arow] = av.w;
    }
    // stage B: thread t loads float4 of W[k0 + t/16][c0 + 4*(t&15) ..]
    {
      int bk = t >> 4, bc = (t & 15) * 4;
      *reinterpret_cast<float4*>(&Bs[bk][bc]) =
          *reinterpret_cast<const float4*>(W + (size_t)(k0 + bk) * FF + c0 + bc);
    }
    __syncthreads();
#pragma unroll
    for (int kk = 0; kk < 16; ++kk) {
      float4 a4 = *reinterpret_cast<float4*>(&Ast[kk][ty * 4]);
      float4 b4 = *reinterpret_cast<float4*>(&Bs[kk][tx * 4]);
      float aa[4] = {a4.x, a4.y, a4.z, a4.w};
      float bb[4] = {b4.x, b4.y, b4.z, b4.w};
#pragma unroll
      for (int i = 0; i < 4; ++i)
#pragma unroll
        for (int j = 0; j < 4; ++j) acc[i][j] += aa[i] * bb[j];
    }
    __syncthreads();
  }
#pragma unroll
  for (int i = 0; i < 4; ++i) {
    int r = r0 + ty * 4 + i;
    if (r < NN) {
#pragma unroll
      for (int j = 0; j < 4; ++j) {
        int c = c0 + tx * 4 + j;
        h[(size_t)r * FF + c] = acc[i][j] + bias[c];
      }
    }
  }
}

// ---------------- beta = softmax(x @ conv_w^T + conv_b) over 3 relations ----------------
__global__ __launch_bounds__(256) void k_beta(const float* __restrict__ x,
                                              const float* __restrict__ cw,
                                              const float* __restrict__ cb,
                                              float* __restrict__ beta) {
  int wid  = (int)((blockIdx.x * (size_t)blockDim.x + threadIdx.x) >> 6);
  int lane = threadIdx.x & 63;
  if (wid >= NN) return;
  float4 xv = *reinterpret_cast<const float4*>(x + (size_t)wid * FF + lane * 4);
  float s[3];
#pragma unroll
  for (int r = 0; r < 3; ++r) {
    float4 wv = *reinterpret_cast<const float4*>(cw + r * FF + lane * 4);
    float p = xv.x * wv.x + xv.y * wv.y + xv.z * wv.z + xv.w * wv.w;
#pragma unroll
    for (int off = 1; off < 64; off <<= 1) p += __shfl_xor(p, off);
    s[r] = p + cb[r];
  }
  float mx = fmaxf(s[0], fmaxf(s[1], s[2]));
  float e0 = expf(s[0] - mx), e1 = expf(s[1] - mx), e2 = expf(s[2] - mx);
  float inv = 1.f / (e0 + e1 + e2);
  if (lane == 0) {
    beta[wid * 3 + 0] = e0 * inv;
    beta[wid * 3 + 1] = e1 * inv;
    beta[wid * 3 + 2] = e2 * inv;
  }
}

// ---------------- al/ar[m,n,h] = sum_d h[n,h,d] * attn_{l,r}[m,h,d] ----------------
__global__ __launch_bounds__(256) void k_alar(const float* __restrict__ h,
                                              const float* __restrict__ attn_l,
                                              const float* __restrict__ attn_r,
                                              float* __restrict__ al,
                                              float* __restrict__ ar) {
  int wid  = (int)((blockIdx.x * (size_t)blockDim.x + threadIdx.x) >> 6);
  int lane = threadIdx.x & 63;
  if (wid >= NN) return;
  float4 hv = *reinterpret_cast<const float4*>(h + (size_t)wid * FF + lane * 4);
  int hh = lane >> 4;
  int dd = (lane & 15) * 4;
#pragma unroll
  for (int m = 0; m < MM; ++m) {
    float4 lv = *reinterpret_cast<const float4*>(attn_l + m * 256 + hh * 64 + dd);
    float4 rv = *reinterpret_cast<const float4*>(attn_r + m * 256 + hh * 64 + dd);
    float pl = hv.x * lv.x + hv.y * lv.y + hv.z * lv.z + hv.w * lv.w;
    float pr = hv.x * rv.x + hv.y * rv.y + hv.z * rv.z + hv.w * rv.w;
#pragma unroll
    for (int off = 1; off < 16; off <<= 1) {
      pl += __shfl_xor(pl, off);
      pr += __shfl_xor(pr, off);
    }
    if ((lane & 15) == 0) {
      al[(size_t)m * NN * 4 + wid * 4 + hh] = pl;
      ar[(size_t)m * NN * 4 + wid * 4 + hh] = pr;
    }
  }
}

// ---------------- pass A: sum of exp(logit) per (dst, head) ----------------
__global__ __launch_bounds__(256) void k_edgesum(const int* __restrict__ e0,
                                                 const int* __restrict__ e1,
                                                 const float* __restrict__ al,
                                                 const float* __restrict__ ar,
                                                 const float* __restrict__ alpha,
                                                 float* __restrict__ sumb) {
  int j = blockIdx.x * blockDim.x + threadIdx.x;
  int m = blockIdx.y;
  if (j >= EE) return;
  const int* e = m ? e1 : e0;
  int src = e[j], dst = e[EE + j];
  float a = alpha[m];
  const float* alm = al + (size_t)m * NN * 4;
  const float* arm = ar + (size_t)m * NN * 4;
  float* sm = sumb + (size_t)m * NN * 4;
#pragma unroll
  for (int hh = 0; hh < 4; ++hh) {
    float logit = (alm[src * 4 + hh] + arm[dst * 4 + hh]) * a;
    atomicAdd(&sm[dst * 4 + hh], expf(logit));
  }
}

// ---------------- pass B: scatter beta-scaled, head-averaged messages ----------------
// one wave per edge; lane = d
__global__ __launch_bounds__(256) void k_edgemsg(const int* __restrict__ e0,
                                                 const int* __restrict__ e1,
                                                 const float* __restrict__ al,
                                                 const float* __restrict__ ar,
                                                 const float* __restrict__ alpha,
                                                 const float* __restrict__ sumb,
                                                 const float* __restrict__ beta,
                                                 const float* __restrict__ h,
                                                 float* __restrict__ out) {
  int lane = threadIdx.x & 63;
  int j = (int)((blockIdx.x * (size_t)blockDim.x + threadIdx.x) >> 6);
  int m = blockIdx.y;
  if (j >= EE) return;
  const int* e = m ? e1 : e0;
  int src = e[j], dst = e[EE + j];
  float w = 0.f;
  if (lane < 4) {
    float logit = (al[(size_t)m * NN * 4 + src * 4 + lane] +
                   ar[(size_t)m * NN * 4 + dst * 4 + lane]) * alpha[m];
    w = expf(logit) / (sumb[(size_t)m * NN * 4 + dst * 4 + lane] + 1e-16f);
  }
  float w0 = __shfl(w, 0), w1 = __shfl(w, 1), w2 = __shfl(w, 2), w3 = __shfl(w, 3);
  float scale = beta[dst * 3 + m] * 0.25f;
  const float* hr = h + (size_t)src * FF;
  float msg = w0 * hr[lane] + w1 * hr[64 + lane] + w2 * hr[128 + lane] + w3 * hr[192 + lane];
  atomicAdd(out + (size_t)dst * 64 + lane, scale * msg);
}

// ---------------- final: add self-relation, relu ----------------
__global__ __launch_bounds__(256) void k_final(const float* __restrict__ h,
                                               const float* __restrict__ beta,
                                               float* __restrict__ out) {
  int t = blockIdx.x * blockDim.x + threadIdx.x;
  if (t >= NN * 64) return;
  int n = t >> 6, d = t & 63;
  const float* hr = h + (size_t)n * FF;
  float self = 0.25f * (hr[d] + hr[64 + d] + hr[128 + d] + hr[192 + d]);
  float v = out[t] + beta[n * 3 + 2] * self;
  out[t] = fmaxf(v, 0.f);
}

extern "C" void kernel_launch(void* const* d_in, const int* in_sizes, int n_in,
                              void* d_out, int out_size, void* d_ws, size_t ws_size,
                              hipStream_t stream) {
  const float* x      = (const float*)d_in[0];
  const float* W      = (const float*)d_in[1];
  const float* b      = (const float*)d_in[2];
  const float* cw     = (const float*)d_in[3];
  const float* cb     = (const float*)d_in[4];
  const float* attn_l = (const float*)d_in[5];
  const float* attn_r = (const float*)d_in[6];
  const float* alpha  = (const float*)d_in[7];
  const int*   e0     = (const int*)d_in[8];
  const int*   e1     = (const int*)d_in[9];
  float* out = (float*)d_out;

  float* ws   = (float*)d_ws;
  float* h    = ws;                          // N*256 = 12.8M floats
  float* al   = h + (size_t)NN * 256;        // 2*N*4
  float* ar   = al + (size_t)2 * NN * 4;     // 2*N*4
  float* beta = ar + (size_t)2 * NN * 4;     // N*3
  float* sumb = beta + (size_t)NN * 3;       // 2*N*4

  hipMemsetAsync(d_out, 0, (size_t)NN * 64 * sizeof(float), stream);
  hipMemsetAsync(sumb, 0, (size_t)2 * NN * 4 * sizeof(float), stream);

  dim3 gg((NN + 63) / 64, 4);
  k_gemm<<<gg, 256, 0, stream>>>(x, W, b, h);

  int nodeBlocks = (NN * 64 + 255) / 256;  // one wave per node, 4 waves/block
  k_beta<<<nodeBlocks, 256, 0, stream>>>(x, cw, cb, beta);
  k_alar<<<nodeBlocks, 256, 0, stream>>>(h, attn_l, attn_r, al, ar);

  dim3 ge((EE + 255) / 256, MM);
  k_edgesum<<<ge, 256, 0, stream>>>(e0, e1, al, ar, alpha, sumb);

  dim3 gm(EE / 4, MM);  // one wave per edge
  k_edgemsg<<<gm, 256, 0, stream>>>(e0, e1, al, ar, alpha, sumb, beta, h, out);

  k_final<<<nodeBlocks, 256, 0, stream>>>(h, beta, out);
}

// Round 2
// 1002.167 us; speedup vs baseline: 1.0685x; 1.0685x over previous
//
#include <hip/hip_runtime.h>
#include <hip/hip_fp16.h>

#define NN 50000
#define FF 256
#define DD 64
#define HH 4
#define EE 1000000
#define MM 2

// ---------------- GEMM: h = x @ W + b   [N,256] = [N,256]@[256,256] ----------------
__global__ __launch_bounds__(256) void k_gemm(const float* __restrict__ x,
                                              const float* __restrict__ W,
                                              const float* __restrict__ bias,
                                              float* __restrict__ h) {
  __shared__ float Ast[16][68];
  __shared__ float Bs[16][68];
  const int t  = threadIdx.x;
  const int tx = t & 15, ty = t >> 4;
  const int r0 = blockIdx.x * 64, c0 = blockIdx.y * 64;
  float acc[4][4] = {};

  for (int k0 = 0; k0 < FF; k0 += 16) {
    {
      int arow = t >> 2, akq = (t & 3) * 4;
      int gr = r0 + arow; if (gr >= NN) gr = NN - 1;
      float4 av = *reinterpret_cast<const float4*>(x + (size_t)gr * FF + k0 + akq);
      Ast[akq + 0][arow] = av.x;
      Ast[akq + 1][arow] = av.y;
      Ast[akq + 2][arow] = av.z;
      Ast[akq + 3][arow] = av.w;
    }
    {
      int bk = t >> 4, bc = (t & 15) * 4;
      *reinterpret_cast<float4*>(&Bs[bk][bc]) =
          *reinterpret_cast<const float4*>(W + (size_t)(k0 + bk) * FF + c0 + bc);
    }
    __syncthreads();
#pragma unroll
    for (int kk = 0; kk < 16; ++kk) {
      float4 a4 = *reinterpret_cast<float4*>(&Ast[kk][ty * 4]);
      float4 b4 = *reinterpret_cast<float4*>(&Bs[kk][tx * 4]);
      float aa[4] = {a4.x, a4.y, a4.z, a4.w};
      float bb[4] = {b4.x, b4.y, b4.z, b4.w};
#pragma unroll
      for (int i = 0; i < 4; ++i)
#pragma unroll
        for (int j = 0; j < 4; ++j) acc[i][j] += aa[i] * bb[j];
    }
    __syncthreads();
  }
#pragma unroll
  for (int i = 0; i < 4; ++i) {
    int r = r0 + ty * 4 + i;
    if (r < NN) {
#pragma unroll
      for (int j = 0; j < 4; ++j) {
        int c = c0 + tx * 4 + j;
        h[(size_t)r * FF + c] = acc[i][j] + bias[c];
      }
    }
  }
}

// ---------------- beta = softmax(x @ conv_w^T + conv_b) over 3 relations ----------------
__global__ __launch_bounds__(256) void k_beta(const float* __restrict__ x,
                                              const float* __restrict__ cw,
                                              const float* __restrict__ cb,
                                              float* __restrict__ beta) {
  int wid  = (int)((blockIdx.x * (size_t)blockDim.x + threadIdx.x) >> 6);
  int lane = threadIdx.x & 63;
  if (wid >= NN) return;
  float4 xv = *reinterpret_cast<const float4*>(x + (size_t)wid * FF + lane * 4);
  float s[3];
#pragma unroll
  for (int r = 0; r < 3; ++r) {
    float4 wv = *reinterpret_cast<const float4*>(cw + r * FF + lane * 4);
    float p = xv.x * wv.x + xv.y * wv.y + xv.z * wv.z + xv.w * wv.w;
#pragma unroll
    for (int off = 1; off < 64; off <<= 1) p += __shfl_xor(p, off);
    s[r] = p + cb[r];
  }
  float mx = fmaxf(s[0], fmaxf(s[1], s[2]));
  float e0 = expf(s[0] - mx), e1 = expf(s[1] - mx), e2 = expf(s[2] - mx);
  float inv = 1.f / (e0 + e1 + e2);
  if (lane == 0) {
    beta[wid * 3 + 0] = e0 * inv;
    beta[wid * 3 + 1] = e1 * inv;
    beta[wid * 3 + 2] = e2 * inv;
  }
}

// ---------------- al/ar + build transposed fp16 h16[n][d][h] ----------------
__global__ __launch_bounds__(256) void k_alar(const float* __restrict__ h,
                                              const float* __restrict__ attn_l,
                                              const float* __restrict__ attn_r,
                                              float* __restrict__ al,
                                              float* __restrict__ ar,
                                              __half* __restrict__ h16) {
  __shared__ __half tile[4][256];
  int widx = threadIdx.x >> 6;
  int wid  = (int)(blockIdx.x * 4 + widx);   // node (grid is exact: 50000 waves)
  int lane = threadIdx.x & 63;
  float4 hv = *reinterpret_cast<const float4*>(h + (size_t)wid * FF + lane * 4);

  // transpose [H][D] -> [D][H] in fp16 via LDS
  float hvq[4] = {hv.x, hv.y, hv.z, hv.w};
#pragma unroll
  for (int q = 0; q < 4; ++q) {
    int e = lane * 4 + q;                    // e = head*64 + d
    tile[widx][((e & 63) << 2) | (e >> 6)] = __float2half(hvq[q]);
  }
  __syncthreads();
  *((uint64_t*)(h16 + (size_t)wid * 256) + lane) = *((const uint64_t*)&tile[widx][lane * 4]);

  int hh = lane >> 4;
  int dd = (lane & 15) * 4;
#pragma unroll
  for (int m = 0; m < MM; ++m) {
    float4 lv = *reinterpret_cast<const float4*>(attn_l + m * 256 + hh * 64 + dd);
    float4 rv = *reinterpret_cast<const float4*>(attn_r + m * 256 + hh * 64 + dd);
    float pl = hv.x * lv.x + hv.y * lv.y + hv.z * lv.z + hv.w * lv.w;
    float pr = hv.x * rv.x + hv.y * rv.y + hv.z * rv.z + hv.w * rv.w;
#pragma unroll
    for (int off = 1; off < 16; off <<= 1) {
      pl += __shfl_xor(pl, off);
      pr += __shfl_xor(pr, off);
    }
    if ((lane & 15) == 0) {
      al[(size_t)m * NN * 4 + wid * 4 + hh] = pl;
      ar[(size_t)m * NN * 4 + wid * 4 + hh] = pr;
    }
  }
}

// ---------------- pass A: sum of exp(logit) per (dst, head); store exp per edge ----------------
__global__ __launch_bounds__(256) void k_edgesum(const int* __restrict__ e0,
                                                 const int* __restrict__ e1,
                                                 const float* __restrict__ al,
                                                 const float* __restrict__ ar,
                                                 const float* __restrict__ alpha,
                                                 float* __restrict__ sumb,
                                                 __half* __restrict__ w16) {
  int j = blockIdx.x * blockDim.x + threadIdx.x;
  int m = blockIdx.y;
  if (j >= EE) return;
  const int* e = m ? e1 : e0;
  int src = e[j], dst = e[EE + j];
  float a = alpha[m];
  const float* alm = al + (size_t)m * NN * 4 + (size_t)src * 4;
  const float* arm = ar + (size_t)m * NN * 4 + (size_t)dst * 4;
  float* sm = sumb + (size_t)m * NN * 4 + (size_t)dst * 4;
  union { __half hx[4]; uint64_t u; } pk;
#pragma unroll
  for (int hh = 0; hh < 4; ++hh) {
    float ex = __expf((alm[hh] + arm[hh]) * a);
    pk.hx[hh] = __float2half(ex);
    atomicAdd(&sm[hh], ex);
  }
  ((uint64_t*)w16)[(size_t)m * EE + j] = pk.u;
}

// ---------------- pass B: scatter beta-scaled head-mixed fp16 messages ----------------
// one wave per edge; lane = d; packed fp16 atomics
__global__ __launch_bounds__(256) void k_edgemsg(const int* __restrict__ e0,
                                                 const int* __restrict__ e1,
                                                 const __half* __restrict__ w16,
                                                 const float* __restrict__ sumb,
                                                 const float* __restrict__ beta,
                                                 const __half* __restrict__ h16,
                                                 __half* __restrict__ out16) {
  int lane = threadIdx.x & 63;
  int j = (int)((blockIdx.x * (size_t)blockDim.x + threadIdx.x) >> 6);
  int m = blockIdx.y;
  const int* e = m ? e1 : e0;
  int src = e[j], dst = e[EE + j];

  float w = 0.f;
  if (lane < 4) {
    float ww = __half2float(w16[((size_t)m * EE + j) * 4 + lane]);
    float S  = sumb[(size_t)m * NN * 4 + (size_t)dst * 4 + lane];
    w = ww / (S + 1e-16f);
  }
  float scale = beta[dst * 3 + m] * 0.25f;
  float w0 = __shfl(w, 0) * scale, w1 = __shfl(w, 1) * scale;
  float w2 = __shfl(w, 2) * scale, w3 = __shfl(w, 3) * scale;

  union { uint64_t u; __half2 p[2]; } hv;
  hv.u = *((const uint64_t*)(h16 + (size_t)src * 256) + lane);  // heads 0..3 at d=lane
  float2 f01 = __half22float2(hv.p[0]);
  float2 f23 = __half22float2(hv.p[1]);
  float msg = w0 * f01.x + w1 * f01.y + w2 * f23.x + w3 * f23.y;

  float nb = __shfl_xor(msg, 1);
  if (!(lane & 1)) {
    __half2 v = __halves2half2(__float2half(msg), __float2half(nb));
    unsafeAtomicAdd((__half2*)(out16 + (size_t)dst * 64 + lane), v);
  }
}

// ---------------- final: add self-relation, relu, fp32 out ----------------
__global__ __launch_bounds__(256) void k_final(const float* __restrict__ h,
                                               const float* __restrict__ beta,
                                               const __half* __restrict__ out16,
                                               float* __restrict__ out) {
  int t = blockIdx.x * blockDim.x + threadIdx.x;
  if (t >= NN * 64) return;
  int n = t >> 6, d = t & 63;
  const float* hr = h + (size_t)n * FF;
  float self = 0.25f * (hr[d] + hr[64 + d] + hr[128 + d] + hr[192 + d]);
  float v = __half2float(out16[t]) + beta[n * 3 + 2] * self;
  out[t] = fmaxf(v, 0.f);
}

extern "C" void kernel_launch(void* const* d_in, const int* in_sizes, int n_in,
                              void* d_out, int out_size, void* d_ws, size_t ws_size,
                              hipStream_t stream) {
  const float* x      = (const float*)d_in[0];
  const float* W      = (const float*)d_in[1];
  const float* b      = (const float*)d_in[2];
  const float* cw     = (const float*)d_in[3];
  const float* cb     = (const float*)d_in[4];
  const float* attn_l = (const float*)d_in[5];
  const float* attn_r = (const float*)d_in[6];
  const float* alpha  = (const float*)d_in[7];
  const int*   e0     = (const int*)d_in[8];
  const int*   e1     = (const int*)d_in[9];
  float* out = (float*)d_out;

  char* p = (char*)d_ws;
  float*  h     = (float*)p;              p += (size_t)NN * 256 * 4;   // 51.2 MB
  __half* h16   = (__half*)p;             p += (size_t)NN * 256 * 2;   // 25.6 MB
  float*  al    = (float*)p;              p += (size_t)2 * NN * 4 * 4; // 1.6 MB
  float*  ar    = (float*)p;              p += (size_t)2 * NN * 4 * 4; // 1.6 MB
  float*  beta  = (float*)p;              p += (size_t)NN * 3 * 4;     // 0.6 MB
  float*  sumb  = (float*)p;              p += (size_t)2 * NN * 4 * 4; // 1.6 MB
  __half* w16   = (__half*)p;             p += (size_t)2 * EE * 4 * 2; // 16 MB
  __half* out16 = (__half*)p;             p += (size_t)NN * 64 * 2;    // 6.4 MB

  hipMemsetAsync(sumb, 0, (size_t)2 * NN * 4 * 4, stream);
  hipMemsetAsync(out16, 0, (size_t)NN * 64 * 2, stream);

  dim3 gg((NN + 63) / 64, 4);
  k_gemm<<<gg, 256, 0, stream>>>(x, W, b, h);

  int nodeBlocks = (NN * 64 + 255) / 256;
  k_beta<<<nodeBlocks, 256, 0, stream>>>(x, cw, cb, beta);
  k_alar<<<nodeBlocks, 256, 0, stream>>>(h, attn_l, attn_r, al, ar, h16);

  dim3 ge((EE + 255) / 256, MM);
  k_edgesum<<<ge, 256, 0, stream>>>(e0, e1, al, ar, alpha, sumb, w16);

  dim3 gm(EE / 4, MM);
  k_edgemsg<<<gm, 256, 0, stream>>>(e0, e1, w16, sumb, beta, h16, out16);

  k_final<<<nodeBlocks, 256, 0, stream>>>(h, beta, out16, out);
}

// Round 3
// 589.094 us; speedup vs baseline: 1.8178x; 1.7012x over previous
//
#include <hip/hip_runtime.h>
#include <hip/hip_fp16.h>

#define NN 50000
#define FF 256
#define DD 64
#define HH 4
#define EE 1000000
#define MM 2

// ---------------- GEMM: h = x @ W + b   [N,256] = [N,256]@[256,256] ----------------
__global__ __launch_bounds__(256) void k_gemm(const float* __restrict__ x,
                                              const float* __restrict__ W,
                                              const float* __restrict__ bias,
                                              float* __restrict__ h) {
  __shared__ float Ast[16][68];
  __shared__ float Bs[16][68];
  const int t  = threadIdx.x;
  const int tx = t & 15, ty = t >> 4;
  const int r0 = blockIdx.x * 64, c0 = blockIdx.y * 64;
  float acc[4][4] = {};

  for (int k0 = 0; k0 < FF; k0 += 16) {
    {
      int arow = t >> 2, akq = (t & 3) * 4;
      int gr = r0 + arow; if (gr >= NN) gr = NN - 1;
      float4 av = *reinterpret_cast<const float4*>(x + (size_t)gr * FF + k0 + akq);
      Ast[akq + 0][arow] = av.x;
      Ast[akq + 1][arow] = av.y;
      Ast[akq + 2][arow] = av.z;
      Ast[akq + 3][arow] = av.w;
    }
    {
      int bk = t >> 4, bc = (t & 15) * 4;
      *reinterpret_cast<float4*>(&Bs[bk][bc]) =
          *reinterpret_cast<const float4*>(W + (size_t)(k0 + bk) * FF + c0 + bc);
    }
    __syncthreads();
#pragma unroll
    for (int kk = 0; kk < 16; ++kk) {
      float4 a4 = *reinterpret_cast<float4*>(&Ast[kk][ty * 4]);
      float4 b4 = *reinterpret_cast<float4*>(&Bs[kk][tx * 4]);
      float aa[4] = {a4.x, a4.y, a4.z, a4.w};
      float bb[4] = {b4.x, b4.y, b4.z, b4.w};
#pragma unroll
      for (int i = 0; i < 4; ++i)
#pragma unroll
        for (int j = 0; j < 4; ++j) acc[i][j] += aa[i] * bb[j];
    }
    __syncthreads();
  }
#pragma unroll
  for (int i = 0; i < 4; ++i) {
    int r = r0 + ty * 4 + i;
    if (r < NN) {
#pragma unroll
      for (int j = 0; j < 4; ++j) {
        int c = c0 + tx * 4 + j;
        h[(size_t)r * FF + c] = acc[i][j] + bias[c];
      }
    }
  }
}

// ---------------- beta = softmax(x @ conv_w^T + conv_b) over 3 relations ----------------
__global__ __launch_bounds__(256) void k_beta(const float* __restrict__ x,
                                              const float* __restrict__ cw,
                                              const float* __restrict__ cb,
                                              float* __restrict__ beta) {
  int wid  = (int)((blockIdx.x * (size_t)blockDim.x + threadIdx.x) >> 6);
  int lane = threadIdx.x & 63;
  if (wid >= NN) return;
  float4 xv = *reinterpret_cast<const float4*>(x + (size_t)wid * FF + lane * 4);
  float s[3];
#pragma unroll
  for (int r = 0; r < 3; ++r) {
    float4 wv = *reinterpret_cast<const float4*>(cw + r * FF + lane * 4);
    float p = xv.x * wv.x + xv.y * wv.y + xv.z * wv.z + xv.w * wv.w;
#pragma unroll
    for (int off = 1; off < 64; off <<= 1) p += __shfl_xor(p, off);
    s[r] = p + cb[r];
  }
  float mx = fmaxf(s[0], fmaxf(s[1], s[2]));
  float e0 = expf(s[0] - mx), e1 = expf(s[1] - mx), e2 = expf(s[2] - mx);
  float inv = 1.f / (e0 + e1 + e2);
  if (lane == 0) {
    beta[wid * 3 + 0] = e0 * inv;
    beta[wid * 3 + 1] = e1 * inv;
    beta[wid * 3 + 2] = e2 * inv;
  }
}

// ---------------- al/ar + build transposed fp16 h16[n][d][h] ----------------
__global__ __launch_bounds__(256) void k_alar(const float* __restrict__ h,
                                              const float* __restrict__ attn_l,
                                              const float* __restrict__ attn_r,
                                              float* __restrict__ al,
                                              float* __restrict__ ar,
                                              __half* __restrict__ h16) {
  __shared__ __half tile[4][256];
  int widx = threadIdx.x >> 6;
  int wid  = (int)(blockIdx.x * 4 + widx);   // node (grid exact: 50000 waves)
  int lane = threadIdx.x & 63;
  float4 hv = *reinterpret_cast<const float4*>(h + (size_t)wid * FF + lane * 4);

  float hvq[4] = {hv.x, hv.y, hv.z, hv.w};
#pragma unroll
  for (int q = 0; q < 4; ++q) {
    int e = lane * 4 + q;                    // e = head*64 + d
    tile[widx][((e & 63) << 2) | (e >> 6)] = __float2half(hvq[q]);
  }
  __syncthreads();
  *((uint64_t*)(h16 + (size_t)wid * 256) + lane) = *((const uint64_t*)&tile[widx][lane * 4]);

  int hh = lane >> 4;
  int dd = (lane & 15) * 4;
#pragma unroll
  for (int m = 0; m < MM; ++m) {
    float4 lv = *reinterpret_cast<const float4*>(attn_l + m * 256 + hh * 64 + dd);
    float4 rv = *reinterpret_cast<const float4*>(attn_r + m * 256 + hh * 64 + dd);
    float pl = hv.x * lv.x + hv.y * lv.y + hv.z * lv.z + hv.w * lv.w;
    float pr = hv.x * rv.x + hv.y * rv.y + hv.z * rv.z + hv.w * rv.w;
#pragma unroll
    for (int off = 1; off < 16; off <<= 1) {
      pl += __shfl_xor(pl, off);
      pr += __shfl_xor(pr, off);
    }
    if ((lane & 15) == 0) {
      al[(size_t)m * NN * 4 + wid * 4 + hh] = pl;
      ar[(size_t)m * NN * 4 + wid * 4 + hh] = pr;
    }
  }
}

// ---------------- histogram of dst ----------------
__global__ __launch_bounds__(256) void k_hist(const int* __restrict__ e0,
                                              const int* __restrict__ e1,
                                              int* __restrict__ cnt) {
  int j = blockIdx.x * blockDim.x + threadIdx.x;
  int m = blockIdx.y;
  if (j >= EE) return;
  const int* e = m ? e1 : e0;
  atomicAdd(&cnt[(size_t)m * NN + e[EE + j]], 1);
}

// ---------------- exclusive scan (one block per metapath) ----------------
#define SCHUNK 49  // ceil(50000/1024)
__global__ __launch_bounds__(1024) void k_scan(const int* __restrict__ cnt,
                                               int* __restrict__ start,
                                               int* __restrict__ off) {
  int m = blockIdx.x;
  const int* c = cnt + (size_t)m * NN;
  int* st = start + (size_t)m * NN;
  int* of = off + (size_t)m * NN;
  __shared__ int part[1024];
  int t = threadIdx.x;
  int lo = t * SCHUNK, hi = min(lo + SCHUNK, NN);
  int s = 0;
  for (int i = lo; i < hi; ++i) s += c[i];
  part[t] = s;
  __syncthreads();
  for (int d = 1; d < 1024; d <<= 1) {
    int v = (t >= d) ? part[t - d] : 0;
    __syncthreads();
    if (t >= d) part[t] += v;
    __syncthreads();
  }
  int base = part[t] - s;
  for (int i = lo; i < hi; ++i) {
    int v = c[i];
    st[i] = base;
    of[i] = base;
    base += v;
  }
}

// ---------------- scatter edges into dst-sorted order, with exp weights ----------------
__global__ __launch_bounds__(256) void k_scatter(const int* __restrict__ e0,
                                                 const int* __restrict__ e1,
                                                 const float* __restrict__ al,
                                                 const float* __restrict__ ar,
                                                 const float* __restrict__ alpha,
                                                 int* __restrict__ off,
                                                 int* __restrict__ src_s,
                                                 unsigned long long* __restrict__ w_s) {
  int j = blockIdx.x * blockDim.x + threadIdx.x;
  int m = blockIdx.y;
  if (j >= EE) return;
  const int* e = m ? e1 : e0;
  int src = e[j], dst = e[EE + j];
  float a = alpha[m];
  float4 av = *reinterpret_cast<const float4*>(al + ((size_t)m * NN + src) * 4);
  float4 rv = *reinterpret_cast<const float4*>(ar + ((size_t)m * NN + dst) * 4);
  union { __half hx[4]; unsigned long long u; } pk;
  pk.hx[0] = __float2half(__expf((av.x + rv.x) * a));
  pk.hx[1] = __float2half(__expf((av.y + rv.y) * a));
  pk.hx[2] = __float2half(__expf((av.z + rv.z) * a));
  pk.hx[3] = __float2half(__expf((av.w + rv.w) * a));
  int pos = atomicAdd(&off[(size_t)m * NN + dst], 1);
  src_s[(size_t)m * EE + pos] = src;
  w_s[(size_t)m * EE + pos] = pk.u;
}

// ---------------- aggregate: one wave per dst, both metapaths + self + relu ----------------
__global__ __launch_bounds__(256) void k_agg(const int* __restrict__ start,
                                             const int* __restrict__ off,
                                             const int* __restrict__ src_s,
                                             const unsigned long long* __restrict__ w_s,
                                             const __half* __restrict__ h16,
                                             const float* __restrict__ beta,
                                             float* __restrict__ out) {
  int lane = threadIdx.x & 63;
  int dst  = (int)((blockIdx.x * (size_t)blockDim.x + threadIdx.x) >> 6);
  if (dst >= NN) return;
  float msg = 0.f;
#pragma unroll
  for (int m = 0; m < MM; ++m) {
    const int* ss = src_s + (size_t)m * EE;
    const unsigned long long* ww = w_s + (size_t)m * EE;
    int p  = start[(size_t)m * NN + dst];
    int pe = off[(size_t)m * NN + dst];
    float a0 = 0.f, a1 = 0.f, a2 = 0.f, a3 = 0.f;
    float S0 = 0.f, S1 = 0.f, S2 = 0.f, S3 = 0.f;
    for (; p + 2 <= pe; p += 2) {
      int sa = ss[p], sb = ss[p + 1];
      unsigned long long wa = ww[p], wb = ww[p + 1];
      unsigned long long ha = *reinterpret_cast<const unsigned long long*>(
          h16 + (size_t)sa * 256 + lane * 4);
      unsigned long long hb = *reinterpret_cast<const unsigned long long*>(
          h16 + (size_t)sb * 256 + lane * 4);
      {
        union { unsigned long long u; __half2 p2[2]; } Wu, Hu;
        Wu.u = wa; Hu.u = ha;
        float2 we01 = __half22float2(Wu.p2[0]), we23 = __half22float2(Wu.p2[1]);
        float2 hh01 = __half22float2(Hu.p2[0]), hh23 = __half22float2(Hu.p2[1]);
        a0 += we01.x * hh01.x; a1 += we01.y * hh01.y;
        a2 += we23.x * hh23.x; a3 += we23.y * hh23.y;
        S0 += we01.x; S1 += we01.y; S2 += we23.x; S3 += we23.y;
      }
      {
        union { unsigned long long u; __half2 p2[2]; } Wu, Hu;
        Wu.u = wb; Hu.u = hb;
        float2 we01 = __half22float2(Wu.p2[0]), we23 = __half22float2(Wu.p2[1]);
        float2 hh01 = __half22float2(Hu.p2[0]), hh23 = __half22float2(Hu.p2[1]);
        a0 += we01.x * hh01.x; a1 += we01.y * hh01.y;
        a2 += we23.x * hh23.x; a3 += we23.y * hh23.y;
        S0 += we01.x; S1 += we01.y; S2 += we23.x; S3 += we23.y;
      }
    }
    if (p < pe) {
      int sa = ss[p];
      unsigned long long wa = ww[p];
      unsigned long long ha = *reinterpret_cast<const unsigned long long*>(
          h16 + (size_t)sa * 256 + lane * 4);
      union { unsigned long long u; __half2 p2[2]; } Wu, Hu;
      Wu.u = wa; Hu.u = ha;
      float2 we01 = __half22float2(Wu.p2[0]), we23 = __half22float2(Wu.p2[1]);
      float2 hh01 = __half22float2(Hu.p2[0]), hh23 = __half22float2(Hu.p2[1]);
      a0 += we01.x * hh01.x; a1 += we01.y * hh01.y;
      a2 += we23.x * hh23.x; a3 += we23.y * hh23.y;
      S0 += we01.x; S1 += we01.y; S2 += we23.x; S3 += we23.y;
    }
    float bm = beta[dst * 3 + m] * 0.25f;
    msg += bm * (a0 / (S0 + 1e-16f) + a1 / (S1 + 1e-16f) +
                 a2 / (S2 + 1e-16f) + a3 / (S3 + 1e-16f));
  }
  // self-relation from h16[dst]
  unsigned long long hs = *reinterpret_cast<const unsigned long long*>(
      h16 + (size_t)dst * 256 + lane * 4);
  union { unsigned long long u; __half2 p2[2]; } Hu;
  Hu.u = hs;
  float2 h01 = __half22float2(Hu.p2[0]), h23 = __half22float2(Hu.p2[1]);
  float self = 0.25f * (h01.x + h01.y + h23.x + h23.y);
  float v = msg + beta[dst * 3 + 2] * self;
  out[(size_t)dst * 64 + lane] = fmaxf(v, 0.f);
}

extern "C" void kernel_launch(void* const* d_in, const int* in_sizes, int n_in,
                              void* d_out, int out_size, void* d_ws, size_t ws_size,
                              hipStream_t stream) {
  const float* x      = (const float*)d_in[0];
  const float* W      = (const float*)d_in[1];
  const float* b      = (const float*)d_in[2];
  const float* cw     = (const float*)d_in[3];
  const float* cb     = (const float*)d_in[4];
  const float* attn_l = (const float*)d_in[5];
  const float* attn_r = (const float*)d_in[6];
  const float* alpha  = (const float*)d_in[7];
  const int*   e0     = (const int*)d_in[8];
  const int*   e1     = (const int*)d_in[9];
  float* out = (float*)d_out;

  char* p = (char*)d_ws;
  float*  h     = (float*)p;               p += (size_t)NN * 256 * 4;   // 51.2 MB
  __half* h16   = (__half*)p;              p += (size_t)NN * 256 * 2;   // 25.6 MB
  float*  al    = (float*)p;               p += (size_t)2 * NN * 4 * 4; // 1.6 MB
  float*  ar    = (float*)p;               p += (size_t)2 * NN * 4 * 4; // 1.6 MB
  float*  beta  = (float*)p;               p += (size_t)NN * 3 * 4;     // 0.6 MB
  int*    cnt   = (int*)p;                 p += (size_t)2 * NN * 4;     // 0.4 MB
  int*    start = (int*)p;                 p += (size_t)2 * NN * 4;     // 0.4 MB
  int*    off   = (int*)p;                 p += (size_t)2 * NN * 4;     // 0.4 MB
  int*    src_s = (int*)p;                 p += (size_t)2 * EE * 4;     // 8 MB
  unsigned long long* w_s = (unsigned long long*)p; p += (size_t)2 * EE * 8; // 16 MB

  hipMemsetAsync(cnt, 0, (size_t)2 * NN * 4, stream);

  dim3 gg((NN + 63) / 64, 4);
  k_gemm<<<gg, 256, 0, stream>>>(x, W, b, h);

  int nodeBlocks = (NN * 64 + 255) / 256;  // 12500: one wave per node
  k_beta<<<nodeBlocks, 256, 0, stream>>>(x, cw, cb, beta);
  k_alar<<<nodeBlocks, 256, 0, stream>>>(h, attn_l, attn_r, al, ar, h16);

  dim3 ge((EE + 255) / 256, MM);
  k_hist<<<ge, 256, 0, stream>>>(e0, e1, cnt);
  k_scan<<<MM, 1024, 0, stream>>>(cnt, start, off);
  k_scatter<<<ge, 256, 0, stream>>>(e0, e1, al, ar, alpha, off, src_s, w_s);

  k_agg<<<nodeBlocks, 256, 0, stream>>>(start, off, src_s, w_s, h16, beta, out);
}